// Round 10
// baseline (1439.490 us; speedup 1.0000x reference)
//
#include <hip/hip_runtime.h>

#define NB 8
#define NPTS 4160
#define NS 1024
#define KS 32
#define NROWS (NB*NS*KS)   /* 262144 */
#define R2 0.25f

__device__ __forceinline__ float fmul_(float a, float b){ return __fmul_rn(a,b); }
__device__ __forceinline__ float fadd_(float a, float b){ return __fadd_rn(a,b); }

// DPP-based argmax step (max value, smallest index on ties).
template<int CTRL>
__device__ __forceinline__ void amax_dpp(float& v, int& i) {
  int sv = __builtin_amdgcn_update_dpp((int)0xBF800000, __float_as_int(v), CTRL, 0xF, 0xF, false);
  int si = __builtin_amdgcn_update_dpp(0x7FFFFFFF, i, CTRL, 0xF, 0xF, false);
  float fv = __int_as_float(sv);
  if (fv > v || (fv == v && si < i)) { v = fv; i = si; }
}

// 64-bit (hi,lo) lexicographic max step via DPP; identity (0,0) never wins.
template<int CTRL>
__device__ __forceinline__ void umax64_dpp(unsigned& hi, unsigned& lo) {
  unsigned shi = (unsigned)__builtin_amdgcn_update_dpp(0, (int)hi, CTRL, 0xF, 0xF, false);
  unsigned slo = (unsigned)__builtin_amdgcn_update_dpp(0, (int)lo, CTRL, 0xF, 0xF, false);
  if (shi > hi || (shi == hi && slo > lo)) { hi = shi; lo = slo; }
}

__device__ __forceinline__ float rdl_f(float v, int lane) {
  return __int_as_float(__builtin_amdgcn_readlane(__float_as_int(v), lane));
}

// ---------------- FPS: one 512-thread block per batch, coords-through-slot --
// r9 chain audit: post-barrier had TWO serialized LDS round-trips (slot keys
// ~120cy, then centroid xs/ys/zs[widx] ~120cy). This version carries the
// winner's coords inside the slot: each wave fetches its candidate's coords
// via uniform readlane (lane bi&63, register bank bi>>9 -- wave-uniform
// switch, no LDS), writes {key,x,y,z}; post-barrier the centroid comes from
// readlane of the already-loaded slot registers. xs/ys/zs LDS eliminated.
// Keys unchanged -> identical selection chain; coords bit-identical.
__global__ __launch_bounds__(512, 2) void k_fps(const float* __restrict__ xyz,
                                                float* __restrict__ out_nx) {
  __shared__ __align__(16) unsigned s_slot[2][8][4];  // {keyhi, keylo, x, y}
  __shared__ unsigned s_zsl[2][8];                    // {z}
  int b = blockIdx.x;
  int tid = threadIdx.x;
  const float* X = xyz + (size_t)b*NPTS*3;
  float px[8], py[8], pz[8], dm[8];
#pragma unroll
  for (int k = 0; k < 8; ++k) {
    int i = tid + (k<<9);
    px[k] = X[3*i]; py[k] = X[3*i+1]; pz[k] = X[3*i+2]; dm[k] = 1e10f;
  }
  float tx = 0.f, ty = 0.f, tz = 0.f, tdm = 1e10f;
  if (tid < 64) {                       // tail points 4096..4159 (wave 0)
    int i = 4096 + tid;
    tx = X[3*i]; ty = X[3*i+1]; tz = X[3*i+2];
  }
  float cx = X[0], cy = X[1], cz = X[2];
  float r0x = cx, r0y = cy, r0z = cz;   // per-thread centroid capture
  float r1x = 0.f, r1y = 0.f, r1z = 0.f;
  __syncthreads();
  for (int it = 1; it < NS; ++it) {
#pragma unroll
    for (int k = 0; k < 8; ++k)
      asm volatile("" : "+v"(px[k]), "+v"(py[k]), "+v"(pz[k]), "+v"(dm[k]));
    asm volatile("" : "+v"(tx), "+v"(ty), "+v"(tz), "+v"(tdm));
#pragma unroll
    for (int k = 0; k < 8; ++k) {
      float dx = px[k]-cx, dy = py[k]-cy, dz = pz[k]-cz;
      float d = fadd_(fadd_(fmul_(dx,dx), fmul_(dy,dy)), fmul_(dz,dz));
      dm[k] = fminf(dm[k], d);
    }
    float a0, a1, a2, a3; int j0, j1, j2, j3;
    { bool c = dm[0] >= dm[1]; a0 = c?dm[0]:dm[1]; j0 = c?tid:tid+512; }
    { bool c = dm[2] >= dm[3]; a1 = c?dm[2]:dm[3]; j1 = c?tid+1024:tid+1536; }
    { bool c = dm[4] >= dm[5]; a2 = c?dm[4]:dm[5]; j2 = c?tid+2048:tid+2560; }
    { bool c = dm[6] >= dm[7]; a3 = c?dm[6]:dm[7]; j3 = c?tid+3072:tid+3584; }
    float b0, b1; int i0, i1;
    { bool c = a0 >= a1; b0 = c?a0:a1; i0 = c?j0:j1; }
    { bool c = a2 >= a3; b1 = c?a2:a3; i1 = c?j2:j3; }
    float best; int bi;
    { bool c = b0 >= b1; best = c?b0:b1; bi = c?i0:i1; }
    if (tid < 64) {
      float dx = tx-cx, dy = ty-cy, dz = tz-cz;
      float d = fadd_(fadd_(fmul_(dx,dx), fmul_(dy,dy)), fmul_(dz,dz));
      tdm = fminf(tdm, d);
      if (tdm > best) { best = tdm; bi = 4096 + tid; }
    }
    amax_dpp<0x111>(best, bi);   // row_shr:1
    amax_dpp<0x112>(best, bi);   // row_shr:2
    amax_dpp<0x114>(best, bi);   // row_shr:4
    amax_dpp<0x118>(best, bi);   // row_shr:8
    amax_dpp<0x142>(best, bi);   // row_bcast:15
    amax_dpp<0x143>(best, bi);   // row_bcast:31
    // wave-uniform candidate (lane 63 holds it); fetch its coords by readlane
    int bi63 = __builtin_amdgcn_readlane(bi, 63);                  // uniform
    int bb63 = __builtin_amdgcn_readlane(__float_as_int(best), 63);
    int lsrc = bi63 & 63;
    int kreg = bi63 >> 9;          // 0..7 register bank, 8 = tail (wave 0)
    float wx, wy, wz;
    switch (kreg) {                // uniform per wave -> scalar branch
      case 0: wx=rdl_f(px[0],lsrc); wy=rdl_f(py[0],lsrc); wz=rdl_f(pz[0],lsrc); break;
      case 1: wx=rdl_f(px[1],lsrc); wy=rdl_f(py[1],lsrc); wz=rdl_f(pz[1],lsrc); break;
      case 2: wx=rdl_f(px[2],lsrc); wy=rdl_f(py[2],lsrc); wz=rdl_f(pz[2],lsrc); break;
      case 3: wx=rdl_f(px[3],lsrc); wy=rdl_f(py[3],lsrc); wz=rdl_f(pz[3],lsrc); break;
      case 4: wx=rdl_f(px[4],lsrc); wy=rdl_f(py[4],lsrc); wz=rdl_f(pz[4],lsrc); break;
      case 5: wx=rdl_f(px[5],lsrc); wy=rdl_f(py[5],lsrc); wz=rdl_f(pz[5],lsrc); break;
      case 6: wx=rdl_f(px[6],lsrc); wy=rdl_f(py[6],lsrc); wz=rdl_f(pz[6],lsrc); break;
      case 7: wx=rdl_f(px[7],lsrc); wy=rdl_f(py[7],lsrc); wz=rdl_f(pz[7],lsrc); break;
      default: wx=rdl_f(tx,lsrc);   wy=rdl_f(ty,lsrc);   wz=rdl_f(tz,lsrc);   break;
    }
    if ((tid & 63) == 0) {         // one lane per wave writes the 20B slot
      unsigned* sp = &s_slot[it & 1][tid >> 6][0];
      *(uint4*)sp = make_uint4((unsigned)bb63, ~(unsigned)bi63,
                               __float_as_uint(wx), __float_as_uint(wy));
      s_zsl[it & 1][tid >> 6] = __float_as_uint(wz);
    }
    asm volatile("s_waitcnt lgkmcnt(0)" ::: "memory");
    __builtin_amdgcn_s_barrier();
    asm volatile("" ::: "memory");
    // lanes 0..7 hold slot[0..7]; reduce keys; centroid via readlane (no LDS)
    uint4 sl = *(const uint4*)&s_slot[it & 1][tid & 7][0];
    unsigned zb = s_zsl[it & 1][tid & 7];
    unsigned khi = sl.x, klo = sl.y;
    umax64_dpp<0x111>(khi, klo);
    umax64_dpp<0x112>(khi, klo);
    umax64_dpp<0x114>(khi, klo);
    unsigned klo7 = (unsigned)__builtin_amdgcn_readlane((int)klo, 7);
    int biw = (int)~klo7;
    int wstar = (biw & 511) >> 6;  // tail (4096+t) -> t<64 -> wave 0: correct
    cx = __int_as_float(__builtin_amdgcn_readlane((int)sl.z, wstar));
    cy = __int_as_float(__builtin_amdgcn_readlane((int)sl.w, wstar));
    cz = __int_as_float(__builtin_amdgcn_readlane((int)zb,   wstar));
    if (it == tid)        { r0x = cx; r0y = cy; r0z = cz; }
    if (it == tid + 512)  { r1x = cx; r1y = cy; r1z = cz; }
  }
  size_t o = (size_t)b*NS*3;
  out_nx[o + (size_t)tid*3]         = r0x;
  out_nx[o + (size_t)tid*3 + 1]     = r0y;
  out_nx[o + (size_t)tid*3 + 2]     = r0z;
  out_nx[o + (size_t)(tid+512)*3]   = r1x;
  out_nx[o + (size_t)(tid+512)*3+1] = r1y;
  out_nx[o + (size_t)(tid+512)*3+2] = r1z;
}

// ---------------- ball query: one wave per query + stats zero-init ----------
__global__ __launch_bounds__(256) void k_query(const float* __restrict__ xyz,
    const float* __restrict__ nx, int* __restrict__ gidx, float* __restrict__ stats) {
  if (blockIdx.x == 0) {            // fused k_init (stats consumed first by k_layer0)
    for (int i = threadIdx.x; i < 1024; i += 256) stats[i] = 0.f;
  }
  int gt = blockIdx.x*256 + threadIdx.x;
  int gw = gt >> 6;
  int lane = threadIdx.x & 63;
  int b = gw >> 10;
  const float* X = xyz + (size_t)b*NPTS*3;
  float qx = nx[(size_t)gw*3], qy = nx[(size_t)gw*3+1], qz = nx[(size_t)gw*3+2];
  float qsq = fadd_(fadd_(fmul_(qx,qx), fmul_(qy,qy)), fmul_(qz,qz));
  float ld = R2; int li = 0x7fffffff;
  float mind = 3.3e38f; int mini = 0x7fffffff;
  for (int c0 = 0; c0 < NPTS; c0 += 64) {
    int p = c0 + lane;
    float d = 3.3e38f; int pi = 0x7fffffff;
    if (p < NPTS) {
      float x = X[p*3], yv = X[p*3+1], z = X[p*3+2];
      float psq = fadd_(fadd_(fmul_(x,x), fmul_(yv,yv)), fmul_(z,z));
      float dot = fadd_(fadd_(fmul_(x,qx), fmul_(yv,qy)), fmul_(z,qz));
      d = fadd_(fadd_(fmul_(-2.f,dot), qsq), psq);
      pi = p;
    }
    if (d < mind || (d == mind && pi < mini)) { mind = d; mini = pi; }
    float c31d = __int_as_float(__builtin_amdgcn_readlane(__float_as_int(ld), 31));
    int   c31i = __builtin_amdgcn_readlane(li, 31);
    bool candp = (d < c31d) || (d == c31d && pi < c31i);
    unsigned long long bm = __ballot(candp);
    while (bm) {
      int src = __builtin_ctzll(bm);
      bm &= bm - 1;
      float cd = __int_as_float(__builtin_amdgcn_readlane(__float_as_int(d), src));
      int   ci = __builtin_amdgcn_readlane(pi, src);
      bool lt = (cd < ld) || (cd == ld && ci < li);
      unsigned long long im = __ballot(lt) & 0xffffffffull;
      float sd = __shfl_up(ld, 1);
      int   si = __shfl_up(li, 1);
      if (im) {
        int pos = __builtin_ctzll(im);
        if (lane < 32 && lt) {
          ld = (lane == pos) ? cd : sd;
          li = (lane == pos) ? ci : si;
        }
      }
    }
  }
#pragma unroll
  for (int off = 32; off >= 1; off >>= 1) {
    float ov = __shfl_down(mind, off);
    int   oi = __shfl_down(mini, off);
    if (ov < mind || (ov == mind && oi < mini)) { mind = ov; mini = oi; }
  }
  int i0 = __builtin_amdgcn_readfirstlane(mini);
  if (lane < KS) {
    gidx[(size_t)gw*KS + lane] = (li == 0x7fffffff) ? i0 : li;
  }
}

// ---------------- layer 0: gather + conv(67->64), 8-row x 8-out tiles ------
__global__ __launch_bounds__(256) void k_layer0(
    const float* __restrict__ xyz, const float* __restrict__ pts,
    const float* __restrict__ nx, const int* __restrict__ gidx,
    const float* __restrict__ W, const float* __restrict__ bias,
    float* __restrict__ y, float* __restrict__ stats) {
  __shared__ float4 sW4[67*16];
  __shared__ float sB[64];
  __shared__ float sStat[128];
  float* sW = (float*)sW4;
  int tid = threadIdx.x;
  for (int i = tid; i < 67*64; i += 256) {
    int c = i >> 6, o = i & 63;
    sW[i] = W[o*67 + c];
  }
  if (tid < 64) sB[tid] = bias[tid];
  if (tid < 128) sStat[tid] = 0.f;
  __syncthreads();
  int och = (tid & 7) * 8;
  int w0i = och >> 2;
  int grow = blockIdx.x*256 + (tid >> 3)*8;
  int b = grow >> 15;
  int q = grow >> 5;
  float qx = nx[(size_t)q*3], qy = nx[(size_t)q*3+1], qz = nx[(size_t)q*3+2];
  int jdx[8];
#pragma unroll
  for (int j = 0; j < 8; ++j) jdx[j] = gidx[grow + j];
  float acc[8][8];
#pragma unroll
  for (int j = 0; j < 8; ++j)
#pragma unroll
    for (int i = 0; i < 8; ++i) acc[j][i] = sB[och + i];
  {
    float4 wa0 = sW4[0*16 + w0i], wa1 = sW4[0*16 + w0i + 1];
    float4 wb0 = sW4[1*16 + w0i], wb1 = sW4[1*16 + w0i + 1];
    float4 wc0 = sW4[2*16 + w0i], wc1 = sW4[2*16 + w0i + 1];
#pragma unroll
    for (int j = 0; j < 8; ++j) {
      size_t pb = (size_t)b*NPTS + jdx[j];
      float r0 = xyz[pb*3]   - qx;
      float r1 = xyz[pb*3+1] - qy;
      float r2 = xyz[pb*3+2] - qz;
      acc[j][0]=fmaf(r0,wa0.x,acc[j][0]); acc[j][1]=fmaf(r0,wa0.y,acc[j][1]);
      acc[j][2]=fmaf(r0,wa0.z,acc[j][2]); acc[j][3]=fmaf(r0,wa0.w,acc[j][3]);
      acc[j][4]=fmaf(r0,wa1.x,acc[j][4]); acc[j][5]=fmaf(r0,wa1.y,acc[j][5]);
      acc[j][6]=fmaf(r0,wa1.z,acc[j][6]); acc[j][7]=fmaf(r0,wa1.w,acc[j][7]);
      acc[j][0]=fmaf(r1,wb0.x,acc[j][0]); acc[j][1]=fmaf(r1,wb0.y,acc[j][1]);
      acc[j][2]=fmaf(r1,wb0.z,acc[j][2]); acc[j][3]=fmaf(r1,wb0.w,acc[j][3]);
      acc[j][4]=fmaf(r1,wb1.x,acc[j][4]); acc[j][5]=fmaf(r1,wb1.y,acc[j][5]);
      acc[j][6]=fmaf(r1,wb1.z,acc[j][6]); acc[j][7]=fmaf(r1,wb1.w,acc[j][7]);
      acc[j][0]=fmaf(r2,wc0.x,acc[j][0]); acc[j][1]=fmaf(r2,wc0.y,acc[j][1]);
      acc[j][2]=fmaf(r2,wc0.z,acc[j][2]); acc[j][3]=fmaf(r2,wc0.w,acc[j][3]);
      acc[j][4]=fmaf(r2,wc1.x,acc[j][4]); acc[j][5]=fmaf(r2,wc1.y,acc[j][5]);
      acc[j][6]=fmaf(r2,wc1.z,acc[j][6]); acc[j][7]=fmaf(r2,wc1.w,acc[j][7]);
    }
  }
#pragma unroll 2
  for (int c4 = 0; c4 < 16; ++c4) {
    float4 wv[8];
#pragma unroll
    for (int ch = 0; ch < 4; ++ch) {
      wv[ch*2]   = sW4[(3 + c4*4 + ch)*16 + w0i];
      wv[ch*2+1] = sW4[(3 + c4*4 + ch)*16 + w0i + 1];
    }
#pragma unroll
    for (int j = 0; j < 8; ++j) {
      float4 v = *((const float4*)(pts + ((size_t)b*NPTS + jdx[j])*64) + c4);
      acc[j][0]=fmaf(v.x,wv[0].x,acc[j][0]); acc[j][1]=fmaf(v.x,wv[0].y,acc[j][1]);
      acc[j][2]=fmaf(v.x,wv[0].z,acc[j][2]); acc[j][3]=fmaf(v.x,wv[0].w,acc[j][3]);
      acc[j][4]=fmaf(v.x,wv[1].x,acc[j][4]); acc[j][5]=fmaf(v.x,wv[1].y,acc[j][5]);
      acc[j][6]=fmaf(v.x,wv[1].z,acc[j][6]); acc[j][7]=fmaf(v.x,wv[1].w,acc[j][7]);
      acc[j][0]=fmaf(v.y,wv[2].x,acc[j][0]); acc[j][1]=fmaf(v.y,wv[2].y,acc[j][1]);
      acc[j][2]=fmaf(v.y,wv[2].z,acc[j][2]); acc[j][3]=fmaf(v.y,wv[2].w,acc[j][3]);
      acc[j][4]=fmaf(v.y,wv[3].x,acc[j][4]); acc[j][5]=fmaf(v.y,wv[3].y,acc[j][5]);
      acc[j][6]=fmaf(v.y,wv[3].z,acc[j][6]); acc[j][7]=fmaf(v.y,wv[3].w,acc[j][7]);
      acc[j][0]=fmaf(v.z,wv[4].x,acc[j][0]); acc[j][1]=fmaf(v.z,wv[4].y,acc[j][1]);
      acc[j][2]=fmaf(v.z,wv[4].z,acc[j][2]); acc[j][3]=fmaf(v.z,wv[4].w,acc[j][3]);
      acc[j][4]=fmaf(v.z,wv[5].x,acc[j][4]); acc[j][5]=fmaf(v.z,wv[5].y,acc[j][5]);
      acc[j][6]=fmaf(v.z,wv[5].z,acc[j][6]); acc[j][7]=fmaf(v.z,wv[5].w,acc[j][7]);
      acc[j][0]=fmaf(v.w,wv[6].x,acc[j][0]); acc[j][1]=fmaf(v.w,wv[6].y,acc[j][1]);
      acc[j][2]=fmaf(v.w,wv[6].z,acc[j][2]); acc[j][3]=fmaf(v.w,wv[6].w,acc[j][3]);
      acc[j][4]=fmaf(v.w,wv[7].x,acc[j][4]); acc[j][5]=fmaf(v.w,wv[7].y,acc[j][5]);
      acc[j][6]=fmaf(v.w,wv[7].z,acc[j][6]); acc[j][7]=fmaf(v.w,wv[7].w,acc[j][7]);
    }
  }
#pragma unroll
  for (int j = 0; j < 8; ++j) {
    float4* Yp = (float4*)(y + (size_t)(grow + j)*64 + och);
    Yp[0] = make_float4(acc[j][0], acc[j][1], acc[j][2], acc[j][3]);
    Yp[1] = make_float4(acc[j][4], acc[j][5], acc[j][6], acc[j][7]);
  }
  float sm[8], sq[8];
#pragma unroll
  for (int i = 0; i < 8; ++i) { sm[i] = 0.f; sq[i] = 0.f; }
#pragma unroll
  for (int j = 0; j < 8; ++j)
#pragma unroll
    for (int i = 0; i < 8; ++i) {
      sm[i] = fadd_(sm[i], acc[j][i]);
      sq[i] = fmaf(acc[j][i], acc[j][i], sq[i]);
    }
#pragma unroll
  for (int i = 0; i < 8; ++i) {
    sm[i] += __shfl_xor(sm[i], 8);  sq[i] += __shfl_xor(sq[i], 8);
    sm[i] += __shfl_xor(sm[i], 16); sq[i] += __shfl_xor(sq[i], 16);
    sm[i] += __shfl_xor(sm[i], 32); sq[i] += __shfl_xor(sq[i], 32);
  }
  if ((tid & 63) < 8) {
#pragma unroll
    for (int i = 0; i < 8; ++i) {
      atomicAdd(&sStat[och + i], sm[i]);
      atomicAdd(&sStat[64 + och + i], sq[i]);
    }
  }
  __syncthreads();
  if (tid < 128) atomicAdd(&stats[tid], sStat[tid]);
}

// ---------------- layer 1: fin0 + BN+relu + conv(64->64), in-place ----------
__global__ __launch_bounds__(256) void k_layer1(
    float* __restrict__ y, const float* __restrict__ W,
    const float* __restrict__ bias, float* stats,
    const float* __restrict__ g0, const float* __restrict__ bb0) {
  __shared__ float4 sW4[64*16];
  __shared__ float sB[64], sSc[64], sSh[64];
  __shared__ float sStat[128];
  float* sW = (float*)sW4;
  int tid = threadIdx.x;
  for (int i = tid; i < 64*64; i += 256) {
    int c = i >> 6, o = i & 63;
    sW[i] = W[o*64 + c];
  }
  if (tid < 64) {            // fused k_fin for layer-0 stats (per-block redundant)
    float s = stats[tid], s2 = stats[64 + tid];
    float mean = s * (1.0f/262144.0f);
    float var = fmaxf(s2 * (1.0f/262144.0f) - mean*mean, 0.f);
    float sc = g0[tid] / sqrtf(var + 1e-5f);
    sSc[tid] = sc; sSh[tid] = bb0[tid] - mean * sc;
    sB[tid] = bias[tid];
  }
  if (tid < 128) sStat[tid] = 0.f;
  __syncthreads();
  int och = (tid & 7) * 8;
  int w0i = och >> 2;
  int grow = blockIdx.x*256 + (tid >> 3)*8;
  float acc[8][8];
#pragma unroll
  for (int j = 0; j < 8; ++j)
#pragma unroll
    for (int i = 0; i < 8; ++i) acc[j][i] = sB[och + i];
#pragma unroll 2
  for (int c4 = 0; c4 < 16; ++c4) {
    float4 wv[8];
#pragma unroll
    for (int ch = 0; ch < 4; ++ch) {
      wv[ch*2]   = sW4[(c4*4 + ch)*16 + w0i];
      wv[ch*2+1] = sW4[(c4*4 + ch)*16 + w0i + 1];
    }
    float sc0 = sSc[c4*4],   sc1 = sSc[c4*4+1], sc2 = sSc[c4*4+2], sc3 = sSc[c4*4+3];
    float sh0 = sSh[c4*4],   sh1 = sSh[c4*4+1], sh2 = sSh[c4*4+2], sh3 = sSh[c4*4+3];
#pragma unroll
    for (int j = 0; j < 8; ++j) {
      float4 v = *((const float4*)(y + (size_t)(grow + j)*64) + c4);
      float r0 = fmaxf(fmaf(v.x, sc0, sh0), 0.f);
      float r1 = fmaxf(fmaf(v.y, sc1, sh1), 0.f);
      float r2 = fmaxf(fmaf(v.z, sc2, sh2), 0.f);
      float r3 = fmaxf(fmaf(v.w, sc3, sh3), 0.f);
      acc[j][0]=fmaf(r0,wv[0].x,acc[j][0]); acc[j][1]=fmaf(r0,wv[0].y,acc[j][1]);
      acc[j][2]=fmaf(r0,wv[0].z,acc[j][2]); acc[j][3]=fmaf(r0,wv[0].w,acc[j][3]);
      acc[j][4]=fmaf(r0,wv[1].x,acc[j][4]); acc[j][5]=fmaf(r0,wv[1].y,acc[j][5]);
      acc[j][6]=fmaf(r0,wv[1].z,acc[j][6]); acc[j][7]=fmaf(r0,wv[1].w,acc[j][7]);
      acc[j][0]=fmaf(r1,wv[2].x,acc[j][0]); acc[j][1]=fmaf(r1,wv[2].y,acc[j][1]);
      acc[j][2]=fmaf(r1,wv[2].z,acc[j][2]); acc[j][3]=fmaf(r1,wv[2].w,acc[j][3]);
      acc[j][4]=fmaf(r1,wv[3].x,acc[j][4]); acc[j][5]=fmaf(r1,wv[3].y,acc[j][5]);
      acc[j][6]=fmaf(r1,wv[3].z,acc[j][6]); acc[j][7]=fmaf(r1,wv[3].w,acc[j][7]);
      acc[j][0]=fmaf(r2,wv[4].x,acc[j][0]); acc[j][1]=fmaf(r2,wv[4].y,acc[j][1]);
      acc[j][2]=fmaf(r2,wv[4].z,acc[j][2]); acc[j][3]=fmaf(r2,wv[4].w,acc[j][3]);
      acc[j][4]=fmaf(r2,wv[5].x,acc[j][4]); acc[j][5]=fmaf(r2,wv[5].y,acc[j][5]);
      acc[j][6]=fmaf(r2,wv[5].z,acc[j][6]); acc[j][7]=fmaf(r2,wv[5].w,acc[j][7]);
      acc[j][0]=fmaf(r3,wv[6].x,acc[j][0]); acc[j][1]=fmaf(r3,wv[6].y,acc[j][1]);
      acc[j][2]=fmaf(r3,wv[6].z,acc[j][2]); acc[j][3]=fmaf(r3,wv[6].w,acc[j][3]);
      acc[j][4]=fmaf(r3,wv[7].x,acc[j][4]); acc[j][5]=fmaf(r3,wv[7].y,acc[j][5]);
      acc[j][6]=fmaf(r3,wv[7].z,acc[j][6]); acc[j][7]=fmaf(r3,wv[7].w,acc[j][7]);
    }
  }
  float sm[8], sq[8];
#pragma unroll
  for (int i = 0; i < 8; ++i) { sm[i] = 0.f; sq[i] = 0.f; }
#pragma unroll
  for (int j = 0; j < 8; ++j)
#pragma unroll
    for (int i = 0; i < 8; ++i) {
      sm[i] = fadd_(sm[i], acc[j][i]);
      sq[i] = fmaf(acc[j][i], acc[j][i], sq[i]);
    }
#pragma unroll
  for (int i = 0; i < 8; ++i) {
    sm[i] += __shfl_xor(sm[i], 8);  sq[i] += __shfl_xor(sq[i], 8);
    sm[i] += __shfl_xor(sm[i], 16); sq[i] += __shfl_xor(sq[i], 16);
    sm[i] += __shfl_xor(sm[i], 32); sq[i] += __shfl_xor(sq[i], 32);
  }
  if ((tid & 63) < 8) {
#pragma unroll
    for (int i = 0; i < 8; ++i) {
      atomicAdd(&sStat[och + i], sm[i]);
      atomicAdd(&sStat[64 + och + i], sq[i]);
    }
  }
  __syncthreads();   // all reads of y done before in-place write
#pragma unroll
  for (int j = 0; j < 8; ++j) {
    float4* Yp = (float4*)(y + (size_t)(grow + j)*64 + och);
    Yp[0] = make_float4(acc[j][0], acc[j][1], acc[j][2], acc[j][3]);
    Yp[1] = make_float4(acc[j][4], acc[j][5], acc[j][6], acc[j][7]);
  }
  if (tid < 128) atomicAdd(&stats[128+tid], sStat[tid]);
}

// ---------------- layer 2: fin1 + BN+relu + conv(64->128) + pool ------------
__global__ __launch_bounds__(256) void k_layer2(
    const float* __restrict__ y, const float* __restrict__ W,
    const float* __restrict__ bias, float* stats,
    float* __restrict__ pmax, float* __restrict__ pmin,
    const float* __restrict__ g1, const float* __restrict__ bb1) {
  __shared__ float4 sW4[64*32];
  __shared__ float sB[128], sSc[64], sSh[64];
  __shared__ float sStat[256];
  float* sW = (float*)sW4;
  int tid = threadIdx.x;
  for (int i = tid; i < 64*128; i += 256) {
    int c = i >> 7, o = i & 127;
    sW[i] = W[o*64 + c];
  }
  if (tid < 128) sB[tid] = bias[tid];
  if (tid < 64) {            // fused k_fin for layer-1 stats
    float s = stats[128 + tid], s2 = stats[192 + tid];
    float mean = s * (1.0f/262144.0f);
    float var = fmaxf(s2 * (1.0f/262144.0f) - mean*mean, 0.f);
    float sc = g1[tid] / sqrtf(var + 1e-5f);
    sSc[tid] = sc; sSh[tid] = bb1[tid] - mean * sc;
  }
  sStat[tid] = 0.f;
  __syncthreads();
  int t = blockIdx.x*256 + tid;
  int g = t >> 4;
  int o0 = (t & 15) * 8;
  int w0i = o0 >> 2;
  float mx[8], mn[8], sm[8], sq[8];
#pragma unroll
  for (int i=0;i<8;++i){ mx[i]=-3.4e38f; mn[i]=3.4e38f; sm[i]=0.f; sq[i]=0.f; }
  const float4* Y4 = (const float4*)(y) + (size_t)g*32*16;
#pragma unroll 1
  for (int half = 0; half < 2; ++half) {   // 16-row tile per pass
    float a[16][8];
#pragma unroll
    for (int j=0;j<16;++j)
#pragma unroll
      for (int i=0;i<8;++i) a[j][i] = sB[o0+i];
#pragma unroll 2
    for (int c4 = 0; c4 < 16; ++c4) {      // weights hoisted over 16 rows
      float4 w[8];
#pragma unroll
      for (int ch = 0; ch < 4; ++ch) {
        w[ch*2]   = sW4[(c4*4+ch)*32 + w0i];
        w[ch*2+1] = sW4[(c4*4+ch)*32 + w0i + 1];
      }
      float sc0=sSc[c4*4], sc1=sSc[c4*4+1], sc2=sSc[c4*4+2], sc3=sSc[c4*4+3];
      float sh0=sSh[c4*4], sh1=sSh[c4*4+1], sh2=sSh[c4*4+2], sh3=sSh[c4*4+3];
#pragma unroll
      for (int j = 0; j < 16; ++j) {
        float4 v = Y4[(half*16+j)*16 + c4];
        float r0 = fmaxf(fmaf(v.x, sc0, sh0), 0.f);
        float r1 = fmaxf(fmaf(v.y, sc1, sh1), 0.f);
        float r2 = fmaxf(fmaf(v.z, sc2, sh2), 0.f);
        float r3 = fmaxf(fmaf(v.w, sc3, sh3), 0.f);
        a[j][0]=fmaf(r0,w[0].x,a[j][0]); a[j][1]=fmaf(r0,w[0].y,a[j][1]);
        a[j][2]=fmaf(r0,w[0].z,a[j][2]); a[j][3]=fmaf(r0,w[0].w,a[j][3]);
        a[j][4]=fmaf(r0,w[1].x,a[j][4]); a[j][5]=fmaf(r0,w[1].y,a[j][5]);
        a[j][6]=fmaf(r0,w[1].z,a[j][6]); a[j][7]=fmaf(r0,w[1].w,a[j][7]);
        a[j][0]=fmaf(r1,w[2].x,a[j][0]); a[j][1]=fmaf(r1,w[2].y,a[j][1]);
        a[j][2]=fmaf(r1,w[2].z,a[j][2]); a[j][3]=fmaf(r1,w[2].w,a[j][3]);
        a[j][4]=fmaf(r1,w[3].x,a[j][4]); a[j][5]=fmaf(r1,w[3].y,a[j][5]);
        a[j][6]=fmaf(r1,w[3].z,a[j][6]); a[j][7]=fmaf(r1,w[3].w,a[j][7]);
        a[j][0]=fmaf(r2,w[4].x,a[j][0]); a[j][1]=fmaf(r2,w[4].y,a[j][1]);
        a[j][2]=fmaf(r2,w[4].z,a[j][2]); a[j][3]=fmaf(r2,w[4].w,a[j][3]);
        a[j][4]=fmaf(r2,w[5].x,a[j][4]); a[j][5]=fmaf(r2,w[5].y,a[j][5]);
        a[j][6]=fmaf(r2,w[5].z,a[j][6]); a[j][7]=fmaf(r2,w[5].w,a[j][7]);
        a[j][0]=fmaf(r3,w[6].x,a[j][0]); a[j][1]=fmaf(r3,w[6].y,a[j][1]);
        a[j][2]=fmaf(r3,w[6].z,a[j][2]); a[j][3]=fmaf(r3,w[6].w,a[j][3]);
        a[j][4]=fmaf(r3,w[7].x,a[j][4]); a[j][5]=fmaf(r3,w[7].y,a[j][5]);
        a[j][6]=fmaf(r3,w[7].z,a[j][6]); a[j][7]=fmaf(r3,w[7].w,a[j][7]);
      }
    }
#pragma unroll
    for (int j = 0; j < 16; ++j)
#pragma unroll
      for (int i = 0; i < 8; ++i) {
        float av = a[j][i];
        mx[i]=fmaxf(mx[i],av); mn[i]=fminf(mn[i],av);
        sm[i]=fadd_(sm[i],av); sq[i]=fmaf(av,av,sq[i]);
      }
  }
  size_t ob = (size_t)g*128 + o0;
#pragma unroll
  for (int i=0;i<8;++i) { pmax[ob+i]=mx[i]; pmin[ob+i]=mn[i]; }
#pragma unroll
  for (int i=0;i<8;++i) {
    atomicAdd(&sStat[o0+i], sm[i]);
    atomicAdd(&sStat[128+o0+i], sq[i]);
  }
  __syncthreads();
  atomicAdd(&stats[256+tid], sStat[tid]);
}

// ---------------- output: fin2 + BN+relu on pooled ----------------
__global__ __launch_bounds__(256) void k_out(const float* __restrict__ pmax,
    const float* __restrict__ pmin, const float* __restrict__ stats,
    const float* __restrict__ g2, const float* __restrict__ bb2,
    float* __restrict__ outp) {
  int t = blockIdx.x*256 + threadIdx.x;
  int o = t & 127;
  float s = stats[256 + o], s2 = stats[384 + o];
  float mean = s * (1.0f/262144.0f);
  float var = fmaxf(s2 * (1.0f/262144.0f) - mean*mean, 0.f);
  float sc = g2[o] / sqrtf(var + 1e-5f);
  float sh = bb2[o] - mean * sc;
  float sel = (sc >= 0.f) ? pmax[t] : pmin[t];
  outp[t] = fmaxf(fmaf(sel, sc, sh), 0.f);
}

extern "C" void kernel_launch(void* const* d_in, const int* in_sizes, int n_in,
                              void* d_out, int out_size, void* d_ws, size_t ws_size,
                              hipStream_t stream) {
  const float* xyz = (const float*)d_in[0];
  const float* pts = (const float*)d_in[1];
  const float* W0  = (const float*)d_in[2];
  const float* b0  = (const float*)d_in[3];
  const float* g0  = (const float*)d_in[4];
  const float* bb0 = (const float*)d_in[5];
  const float* W1  = (const float*)d_in[6];
  const float* b1  = (const float*)d_in[7];
  const float* g1  = (const float*)d_in[8];
  const float* bb1 = (const float*)d_in[9];
  const float* W2  = (const float*)d_in[10];
  const float* b2  = (const float*)d_in[11];
  const float* g2  = (const float*)d_in[12];
  const float* bb2 = (const float*)d_in[13];
  float* out_nx = (float*)d_out;
  float* out_np = out_nx + (size_t)NB*NS*3;
  float* ws = (float*)d_ws;
  float* stats = ws;                               // 1024 floats
  int* gidx = (int*)(ws + 1024);                   // NROWS ints
  float* ybuf = ws + 1024 + NROWS;                 // NROWS*64 floats
  float* pmax = ybuf + (size_t)NROWS*64;           // NB*NS*128
  float* pmin = pmax + (size_t)NB*NS*128;          // NB*NS*128

  k_fps<<<NB, 512, 0, stream>>>(xyz, out_nx);
  k_query<<<2048, 256, 0, stream>>>(xyz, out_nx, gidx, stats);
  k_layer0<<<1024, 256, 0, stream>>>(xyz, pts, out_nx, gidx, W0, b0, ybuf, stats);
  k_layer1<<<1024, 256, 0, stream>>>(ybuf, W1, b1, stats, g0, bb0);
  k_layer2<<<512, 256, 0, stream>>>(ybuf, W2, b2, stats, pmax, pmin, g1, bb1);
  k_out<<<4096, 256, 0, stream>>>(pmax, pmin, stats, g2, bb2, out_np);
}

// Round 11
// 1219.694 us; speedup vs baseline: 1.1802x; 1.1802x over previous
//
#include <hip/hip_runtime.h>

#define NB 8
#define NPTS 4160
#define NS 1024
#define KS 32
#define NROWS (NB*NS*KS)   /* 262144 */
#define R2 0.25f

__device__ __forceinline__ float fmul_(float a, float b){ return __fmul_rn(a,b); }
__device__ __forceinline__ float fadd_(float a, float b){ return __fadd_rn(a,b); }

// DPP-based argmax step (max value, smallest index on ties).
template<int CTRL>
__device__ __forceinline__ void amax_dpp(float& v, int& i) {
  int sv = __builtin_amdgcn_update_dpp((int)0xBF800000, __float_as_int(v), CTRL, 0xF, 0xF, false);
  int si = __builtin_amdgcn_update_dpp(0x7FFFFFFF, i, CTRL, 0xF, 0xF, false);
  float fv = __int_as_float(sv);
  if (fv > v || (fv == v && si < i)) { v = fv; i = si; }
}

// 64-bit (hi,lo) lexicographic max step via DPP; identity (0,0) never wins.
template<int CTRL>
__device__ __forceinline__ void umax64_dpp(unsigned& hi, unsigned& lo) {
  unsigned shi = (unsigned)__builtin_amdgcn_update_dpp(0, (int)hi, CTRL, 0xF, 0xF, false);
  unsigned slo = (unsigned)__builtin_amdgcn_update_dpp(0, (int)lo, CTRL, 0xF, 0xF, false);
  if (shi > hi || (shi == hi && slo > lo)) { hi = shi; lo = slo; }
}

// ---------------- FPS: one 512-thread block per batch (r5 body, best) -------
// REVERT of r10's coords-through-slot (1179us, +23%): its pre-barrier
// readlane+9-way-switch serialization (~300cy) exceeded the ~120cy saved on
// the post-barrier centroid read. This r5 body is the best measured (957us,
// ~935ns/iter ~= latency-chain floor at the env-fixed ~1.1 GHz, r6 ballast).
__global__ __launch_bounds__(512, 2) void k_fps(const float* __restrict__ xyz,
                                                float* __restrict__ out_nx) {
  __shared__ float xs[NPTS], ys[NPTS], zs[NPTS];      // 48.8 KB
  __shared__ unsigned long long s_slot[2][8];         // ping-pong wave keys
  int b = blockIdx.x;
  int tid = threadIdx.x;
  const float* X = xyz + (size_t)b*NPTS*3;
  for (int i = tid; i < NPTS; i += 512) {
    xs[i] = X[3*i]; ys[i] = X[3*i+1]; zs[i] = X[3*i+2];
  }
  float px[8], py[8], pz[8], dm[8];
#pragma unroll
  for (int k = 0; k < 8; ++k) {
    int i = tid + (k<<9);
    px[k] = X[3*i]; py[k] = X[3*i+1]; pz[k] = X[3*i+2]; dm[k] = 1e10f;
  }
  float tx = 0.f, ty = 0.f, tz = 0.f, tdm = 1e10f;
  if (tid < 64) {                       // tail points 4096..4159 (wave 0)
    int i = 4096 + tid;
    tx = X[3*i]; ty = X[3*i+1]; tz = X[3*i+2];
  }
  float cx = X[0], cy = X[1], cz = X[2];
  float r0x = cx, r0y = cy, r0z = cz;   // per-thread centroid capture
  float r1x = 0.f, r1y = 0.f, r1z = 0.f;
  __syncthreads();
  for (int it = 1; it < NS; ++it) {
#pragma unroll
    for (int k = 0; k < 8; ++k)
      asm volatile("" : "+v"(px[k]), "+v"(py[k]), "+v"(pz[k]), "+v"(dm[k]));
    asm volatile("" : "+v"(tx), "+v"(ty), "+v"(tz), "+v"(tdm));
#pragma unroll
    for (int k = 0; k < 8; ++k) {
      float dx = px[k]-cx, dy = py[k]-cy, dz = pz[k]-cz;
      float d = fadd_(fadd_(fmul_(dx,dx), fmul_(dy,dy)), fmul_(dz,dz));
      dm[k] = fminf(dm[k], d);
    }
    float a0, a1, a2, a3; int j0, j1, j2, j3;
    { bool c = dm[0] >= dm[1]; a0 = c?dm[0]:dm[1]; j0 = c?tid:tid+512; }
    { bool c = dm[2] >= dm[3]; a1 = c?dm[2]:dm[3]; j1 = c?tid+1024:tid+1536; }
    { bool c = dm[4] >= dm[5]; a2 = c?dm[4]:dm[5]; j2 = c?tid+2048:tid+2560; }
    { bool c = dm[6] >= dm[7]; a3 = c?dm[6]:dm[7]; j3 = c?tid+3072:tid+3584; }
    float b0, b1; int i0, i1;
    { bool c = a0 >= a1; b0 = c?a0:a1; i0 = c?j0:j1; }
    { bool c = a2 >= a3; b1 = c?a2:a3; i1 = c?j2:j3; }
    float best; int bi;
    { bool c = b0 >= b1; best = c?b0:b1; bi = c?i0:i1; }
    if (tid < 64) {
      float dx = tx-cx, dy = ty-cy, dz = tz-cz;
      float d = fadd_(fadd_(fmul_(dx,dx), fmul_(dy,dy)), fmul_(dz,dz));
      tdm = fminf(tdm, d);
      if (tdm > best) { best = tdm; bi = 4096 + tid; }
    }
    amax_dpp<0x111>(best, bi);   // row_shr:1
    amax_dpp<0x112>(best, bi);   // row_shr:2
    amax_dpp<0x114>(best, bi);   // row_shr:4
    amax_dpp<0x118>(best, bi);   // row_shr:8
    amax_dpp<0x142>(best, bi);   // row_bcast:15
    amax_dpp<0x143>(best, bi);   // row_bcast:31
    if ((tid & 63) == 63) {
      s_slot[it & 1][tid >> 6] =
        ((unsigned long long)__float_as_uint(best) << 32)
        | (unsigned long long)(unsigned)(~(unsigned)bi);
    }
    asm volatile("s_waitcnt lgkmcnt(0)" ::: "memory");
    __builtin_amdgcn_s_barrier();
    asm volatile("" ::: "memory");
    unsigned long long kk = s_slot[it & 1][tid & 7];
    unsigned khi = (unsigned)(kk >> 32), klo = (unsigned)kk;
    umax64_dpp<0x111>(khi, klo);
    umax64_dpp<0x112>(khi, klo);
    umax64_dpp<0x114>(khi, klo);
    int widx = (int)~(unsigned)__builtin_amdgcn_readlane((int)klo, 7);
    cx = xs[widx]; cy = ys[widx]; cz = zs[widx];
    if (it == tid)        { r0x = cx; r0y = cy; r0z = cz; }
    if (it == tid + 512)  { r1x = cx; r1y = cy; r1z = cz; }
  }
  size_t o = (size_t)b*NS*3;
  out_nx[o + (size_t)tid*3]         = r0x;
  out_nx[o + (size_t)tid*3 + 1]     = r0y;
  out_nx[o + (size_t)tid*3 + 2]     = r0z;
  out_nx[o + (size_t)(tid+512)*3]   = r1x;
  out_nx[o + (size_t)(tid+512)*3+1] = r1y;
  out_nx[o + (size_t)(tid+512)*3+2] = r1z;
}

// ---------------- ball query: one wave per query + stats zero-init ----------
__global__ __launch_bounds__(256) void k_query(const float* __restrict__ xyz,
    const float* __restrict__ nx, int* __restrict__ gidx, float* __restrict__ stats) {
  if (blockIdx.x == 0) {            // fused k_init (stats consumed first by k_layer0)
    for (int i = threadIdx.x; i < 1024; i += 256) stats[i] = 0.f;
  }
  int gt = blockIdx.x*256 + threadIdx.x;
  int gw = gt >> 6;
  int lane = threadIdx.x & 63;
  int b = gw >> 10;
  const float* X = xyz + (size_t)b*NPTS*3;
  float qx = nx[(size_t)gw*3], qy = nx[(size_t)gw*3+1], qz = nx[(size_t)gw*3+2];
  float qsq = fadd_(fadd_(fmul_(qx,qx), fmul_(qy,qy)), fmul_(qz,qz));
  float ld = R2; int li = 0x7fffffff;
  float mind = 3.3e38f; int mini = 0x7fffffff;
  for (int c0 = 0; c0 < NPTS; c0 += 64) {
    int p = c0 + lane;
    float d = 3.3e38f; int pi = 0x7fffffff;
    if (p < NPTS) {
      float x = X[p*3], yv = X[p*3+1], z = X[p*3+2];
      float psq = fadd_(fadd_(fmul_(x,x), fmul_(yv,yv)), fmul_(z,z));
      float dot = fadd_(fadd_(fmul_(x,qx), fmul_(yv,qy)), fmul_(z,qz));
      d = fadd_(fadd_(fmul_(-2.f,dot), qsq), psq);
      pi = p;
    }
    if (d < mind || (d == mind && pi < mini)) { mind = d; mini = pi; }
    float c31d = __int_as_float(__builtin_amdgcn_readlane(__float_as_int(ld), 31));
    int   c31i = __builtin_amdgcn_readlane(li, 31);
    bool candp = (d < c31d) || (d == c31d && pi < c31i);
    unsigned long long bm = __ballot(candp);
    while (bm) {
      int src = __builtin_ctzll(bm);
      bm &= bm - 1;
      float cd = __int_as_float(__builtin_amdgcn_readlane(__float_as_int(d), src));
      int   ci = __builtin_amdgcn_readlane(pi, src);
      bool lt = (cd < ld) || (cd == ld && ci < li);
      unsigned long long im = __ballot(lt) & 0xffffffffull;
      float sd = __shfl_up(ld, 1);
      int   si = __shfl_up(li, 1);
      if (im) {
        int pos = __builtin_ctzll(im);
        if (lane < 32 && lt) {
          ld = (lane == pos) ? cd : sd;
          li = (lane == pos) ? ci : si;
        }
      }
    }
  }
#pragma unroll
  for (int off = 32; off >= 1; off >>= 1) {
    float ov = __shfl_down(mind, off);
    int   oi = __shfl_down(mini, off);
    if (ov < mind || (ov == mind && oi < mini)) { mind = ov; mini = oi; }
  }
  int i0 = __builtin_amdgcn_readfirstlane(mini);
  if (lane < KS) {
    gidx[(size_t)gw*KS + lane] = (li == 0x7fffffff) ? i0 : li;
  }
}

// ---------------- layer 0: gather + conv(67->64), 8-row x 8-out tiles ------
__global__ __launch_bounds__(256) void k_layer0(
    const float* __restrict__ xyz, const float* __restrict__ pts,
    const float* __restrict__ nx, const int* __restrict__ gidx,
    const float* __restrict__ W, const float* __restrict__ bias,
    float* __restrict__ y, float* __restrict__ stats) {
  __shared__ float4 sW4[67*16];
  __shared__ float sB[64];
  __shared__ float sStat[128];
  float* sW = (float*)sW4;
  int tid = threadIdx.x;
  for (int i = tid; i < 67*64; i += 256) {
    int c = i >> 6, o = i & 63;
    sW[i] = W[o*67 + c];
  }
  if (tid < 64) sB[tid] = bias[tid];
  if (tid < 128) sStat[tid] = 0.f;
  __syncthreads();
  int och = (tid & 7) * 8;
  int w0i = och >> 2;
  int grow = blockIdx.x*256 + (tid >> 3)*8;
  int b = grow >> 15;
  int q = grow >> 5;
  float qx = nx[(size_t)q*3], qy = nx[(size_t)q*3+1], qz = nx[(size_t)q*3+2];
  int jdx[8];
#pragma unroll
  for (int j = 0; j < 8; ++j) jdx[j] = gidx[grow + j];
  float acc[8][8];
#pragma unroll
  for (int j = 0; j < 8; ++j)
#pragma unroll
    for (int i = 0; i < 8; ++i) acc[j][i] = sB[och + i];
  {
    float4 wa0 = sW4[0*16 + w0i], wa1 = sW4[0*16 + w0i + 1];
    float4 wb0 = sW4[1*16 + w0i], wb1 = sW4[1*16 + w0i + 1];
    float4 wc0 = sW4[2*16 + w0i], wc1 = sW4[2*16 + w0i + 1];
#pragma unroll
    for (int j = 0; j < 8; ++j) {
      size_t pb = (size_t)b*NPTS + jdx[j];
      float r0 = xyz[pb*3]   - qx;
      float r1 = xyz[pb*3+1] - qy;
      float r2 = xyz[pb*3+2] - qz;
      acc[j][0]=fmaf(r0,wa0.x,acc[j][0]); acc[j][1]=fmaf(r0,wa0.y,acc[j][1]);
      acc[j][2]=fmaf(r0,wa0.z,acc[j][2]); acc[j][3]=fmaf(r0,wa0.w,acc[j][3]);
      acc[j][4]=fmaf(r0,wa1.x,acc[j][4]); acc[j][5]=fmaf(r0,wa1.y,acc[j][5]);
      acc[j][6]=fmaf(r0,wa1.z,acc[j][6]); acc[j][7]=fmaf(r0,wa1.w,acc[j][7]);
      acc[j][0]=fmaf(r1,wb0.x,acc[j][0]); acc[j][1]=fmaf(r1,wb0.y,acc[j][1]);
      acc[j][2]=fmaf(r1,wb0.z,acc[j][2]); acc[j][3]=fmaf(r1,wb0.w,acc[j][3]);
      acc[j][4]=fmaf(r1,wb1.x,acc[j][4]); acc[j][5]=fmaf(r1,wb1.y,acc[j][5]);
      acc[j][6]=fmaf(r1,wb1.z,acc[j][6]); acc[j][7]=fmaf(r1,wb1.w,acc[j][7]);
      acc[j][0]=fmaf(r2,wc0.x,acc[j][0]); acc[j][1]=fmaf(r2,wc0.y,acc[j][1]);
      acc[j][2]=fmaf(r2,wc0.z,acc[j][2]); acc[j][3]=fmaf(r2,wc0.w,acc[j][3]);
      acc[j][4]=fmaf(r2,wc1.x,acc[j][4]); acc[j][5]=fmaf(r2,wc1.y,acc[j][5]);
      acc[j][6]=fmaf(r2,wc1.z,acc[j][6]); acc[j][7]=fmaf(r2,wc1.w,acc[j][7]);
    }
  }
#pragma unroll 2
  for (int c4 = 0; c4 < 16; ++c4) {
    float4 wv[8];
#pragma unroll
    for (int ch = 0; ch < 4; ++ch) {
      wv[ch*2]   = sW4[(3 + c4*4 + ch)*16 + w0i];
      wv[ch*2+1] = sW4[(3 + c4*4 + ch)*16 + w0i + 1];
    }
#pragma unroll
    for (int j = 0; j < 8; ++j) {
      float4 v = *((const float4*)(pts + ((size_t)b*NPTS + jdx[j])*64) + c4);
      acc[j][0]=fmaf(v.x,wv[0].x,acc[j][0]); acc[j][1]=fmaf(v.x,wv[0].y,acc[j][1]);
      acc[j][2]=fmaf(v.x,wv[0].z,acc[j][2]); acc[j][3]=fmaf(v.x,wv[0].w,acc[j][3]);
      acc[j][4]=fmaf(v.x,wv[1].x,acc[j][4]); acc[j][5]=fmaf(v.x,wv[1].y,acc[j][5]);
      acc[j][6]=fmaf(v.x,wv[1].z,acc[j][6]); acc[j][7]=fmaf(v.x,wv[1].w,acc[j][7]);
      acc[j][0]=fmaf(v.y,wv[2].x,acc[j][0]); acc[j][1]=fmaf(v.y,wv[2].y,acc[j][1]);
      acc[j][2]=fmaf(v.y,wv[2].z,acc[j][2]); acc[j][3]=fmaf(v.y,wv[2].w,acc[j][3]);
      acc[j][4]=fmaf(v.y,wv[3].x,acc[j][4]); acc[j][5]=fmaf(v.y,wv[3].y,acc[j][5]);
      acc[j][6]=fmaf(v.y,wv[3].z,acc[j][6]); acc[j][7]=fmaf(v.y,wv[3].w,acc[j][7]);
      acc[j][0]=fmaf(v.z,wv[4].x,acc[j][0]); acc[j][1]=fmaf(v.z,wv[4].y,acc[j][1]);
      acc[j][2]=fmaf(v.z,wv[4].z,acc[j][2]); acc[j][3]=fmaf(v.z,wv[4].w,acc[j][3]);
      acc[j][4]=fmaf(v.z,wv[5].x,acc[j][4]); acc[j][5]=fmaf(v.z,wv[5].y,acc[j][5]);
      acc[j][6]=fmaf(v.z,wv[5].z,acc[j][6]); acc[j][7]=fmaf(v.z,wv[5].w,acc[j][7]);
      acc[j][0]=fmaf(v.w,wv[6].x,acc[j][0]); acc[j][1]=fmaf(v.w,wv[6].y,acc[j][1]);
      acc[j][2]=fmaf(v.w,wv[6].z,acc[j][2]); acc[j][3]=fmaf(v.w,wv[6].w,acc[j][3]);
      acc[j][4]=fmaf(v.w,wv[7].x,acc[j][4]); acc[j][5]=fmaf(v.w,wv[7].y,acc[j][5]);
      acc[j][6]=fmaf(v.w,wv[7].z,acc[j][6]); acc[j][7]=fmaf(v.w,wv[7].w,acc[j][7]);
    }
  }
#pragma unroll
  for (int j = 0; j < 8; ++j) {
    float4* Yp = (float4*)(y + (size_t)(grow + j)*64 + och);
    Yp[0] = make_float4(acc[j][0], acc[j][1], acc[j][2], acc[j][3]);
    Yp[1] = make_float4(acc[j][4], acc[j][5], acc[j][6], acc[j][7]);
  }
  float sm[8], sq[8];
#pragma unroll
  for (int i = 0; i < 8; ++i) { sm[i] = 0.f; sq[i] = 0.f; }
#pragma unroll
  for (int j = 0; j < 8; ++j)
#pragma unroll
    for (int i = 0; i < 8; ++i) {
      sm[i] = fadd_(sm[i], acc[j][i]);
      sq[i] = fmaf(acc[j][i], acc[j][i], sq[i]);
    }
#pragma unroll
  for (int i = 0; i < 8; ++i) {
    sm[i] += __shfl_xor(sm[i], 8);  sq[i] += __shfl_xor(sq[i], 8);
    sm[i] += __shfl_xor(sm[i], 16); sq[i] += __shfl_xor(sq[i], 16);
    sm[i] += __shfl_xor(sm[i], 32); sq[i] += __shfl_xor(sq[i], 32);
  }
  if ((tid & 63) < 8) {
#pragma unroll
    for (int i = 0; i < 8; ++i) {
      atomicAdd(&sStat[och + i], sm[i]);
      atomicAdd(&sStat[64 + och + i], sq[i]);
    }
  }
  __syncthreads();
  if (tid < 128) atomicAdd(&stats[tid], sStat[tid]);
}

// ---------------- layer 1: fin0 + BN+relu + conv(64->64), in-place ----------
__global__ __launch_bounds__(256) void k_layer1(
    float* __restrict__ y, const float* __restrict__ W,
    const float* __restrict__ bias, float* stats,
    const float* __restrict__ g0, const float* __restrict__ bb0) {
  __shared__ float4 sW4[64*16];
  __shared__ float sB[64], sSc[64], sSh[64];
  __shared__ float sStat[128];
  float* sW = (float*)sW4;
  int tid = threadIdx.x;
  for (int i = tid; i < 64*64; i += 256) {
    int c = i >> 6, o = i & 63;
    sW[i] = W[o*64 + c];
  }
  if (tid < 64) {            // fused k_fin for layer-0 stats (per-block redundant)
    float s = stats[tid], s2 = stats[64 + tid];
    float mean = s * (1.0f/262144.0f);
    float var = fmaxf(s2 * (1.0f/262144.0f) - mean*mean, 0.f);
    float sc = g0[tid] / sqrtf(var + 1e-5f);
    sSc[tid] = sc; sSh[tid] = bb0[tid] - mean * sc;
    sB[tid] = bias[tid];
  }
  if (tid < 128) sStat[tid] = 0.f;
  __syncthreads();
  int och = (tid & 7) * 8;
  int w0i = och >> 2;
  int grow = blockIdx.x*256 + (tid >> 3)*8;
  float acc[8][8];
#pragma unroll
  for (int j = 0; j < 8; ++j)
#pragma unroll
    for (int i = 0; i < 8; ++i) acc[j][i] = sB[och + i];
#pragma unroll 2
  for (int c4 = 0; c4 < 16; ++c4) {
    float4 wv[8];
#pragma unroll
    for (int ch = 0; ch < 4; ++ch) {
      wv[ch*2]   = sW4[(c4*4 + ch)*16 + w0i];
      wv[ch*2+1] = sW4[(c4*4 + ch)*16 + w0i + 1];
    }
    float sc0 = sSc[c4*4],   sc1 = sSc[c4*4+1], sc2 = sSc[c4*4+2], sc3 = sSc[c4*4+3];
    float sh0 = sSh[c4*4],   sh1 = sSh[c4*4+1], sh2 = sSh[c4*4+2], sh3 = sSh[c4*4+3];
#pragma unroll
    for (int j = 0; j < 8; ++j) {
      float4 v = *((const float4*)(y + (size_t)(grow + j)*64) + c4);
      float r0 = fmaxf(fmaf(v.x, sc0, sh0), 0.f);
      float r1 = fmaxf(fmaf(v.y, sc1, sh1), 0.f);
      float r2 = fmaxf(fmaf(v.z, sc2, sh2), 0.f);
      float r3 = fmaxf(fmaf(v.w, sc3, sh3), 0.f);
      acc[j][0]=fmaf(r0,wv[0].x,acc[j][0]); acc[j][1]=fmaf(r0,wv[0].y,acc[j][1]);
      acc[j][2]=fmaf(r0,wv[0].z,acc[j][2]); acc[j][3]=fmaf(r0,wv[0].w,acc[j][3]);
      acc[j][4]=fmaf(r0,wv[1].x,acc[j][4]); acc[j][5]=fmaf(r0,wv[1].y,acc[j][5]);
      acc[j][6]=fmaf(r0,wv[1].z,acc[j][6]); acc[j][7]=fmaf(r0,wv[1].w,acc[j][7]);
      acc[j][0]=fmaf(r1,wv[2].x,acc[j][0]); acc[j][1]=fmaf(r1,wv[2].y,acc[j][1]);
      acc[j][2]=fmaf(r1,wv[2].z,acc[j][2]); acc[j][3]=fmaf(r1,wv[2].w,acc[j][3]);
      acc[j][4]=fmaf(r1,wv[3].x,acc[j][4]); acc[j][5]=fmaf(r1,wv[3].y,acc[j][5]);
      acc[j][6]=fmaf(r1,wv[3].z,acc[j][6]); acc[j][7]=fmaf(r1,wv[3].w,acc[j][7]);
      acc[j][0]=fmaf(r2,wv[4].x,acc[j][0]); acc[j][1]=fmaf(r2,wv[4].y,acc[j][1]);
      acc[j][2]=fmaf(r2,wv[4].z,acc[j][2]); acc[j][3]=fmaf(r2,wv[4].w,acc[j][3]);
      acc[j][4]=fmaf(r2,wv[5].x,acc[j][4]); acc[j][5]=fmaf(r2,wv[5].y,acc[j][5]);
      acc[j][6]=fmaf(r2,wv[5].z,acc[j][6]); acc[j][7]=fmaf(r2,wv[5].w,acc[j][7]);
      acc[j][0]=fmaf(r3,wv[6].x,acc[j][0]); acc[j][1]=fmaf(r3,wv[6].y,acc[j][1]);
      acc[j][2]=fmaf(r3,wv[6].z,acc[j][2]); acc[j][3]=fmaf(r3,wv[6].w,acc[j][3]);
      acc[j][4]=fmaf(r3,wv[7].x,acc[j][4]); acc[j][5]=fmaf(r3,wv[7].y,acc[j][5]);
      acc[j][6]=fmaf(r3,wv[7].z,acc[j][6]); acc[j][7]=fmaf(r3,wv[7].w,acc[j][7]);
    }
  }
  float sm[8], sq[8];
#pragma unroll
  for (int i = 0; i < 8; ++i) { sm[i] = 0.f; sq[i] = 0.f; }
#pragma unroll
  for (int j = 0; j < 8; ++j)
#pragma unroll
    for (int i = 0; i < 8; ++i) {
      sm[i] = fadd_(sm[i], acc[j][i]);
      sq[i] = fmaf(acc[j][i], acc[j][i], sq[i]);
    }
#pragma unroll
  for (int i = 0; i < 8; ++i) {
    sm[i] += __shfl_xor(sm[i], 8);  sq[i] += __shfl_xor(sq[i], 8);
    sm[i] += __shfl_xor(sm[i], 16); sq[i] += __shfl_xor(sq[i], 16);
    sm[i] += __shfl_xor(sm[i], 32); sq[i] += __shfl_xor(sq[i], 32);
  }
  if ((tid & 63) < 8) {
#pragma unroll
    for (int i = 0; i < 8; ++i) {
      atomicAdd(&sStat[och + i], sm[i]);
      atomicAdd(&sStat[64 + och + i], sq[i]);
    }
  }
  __syncthreads();   // all reads of y done before in-place write
#pragma unroll
  for (int j = 0; j < 8; ++j) {
    float4* Yp = (float4*)(y + (size_t)(grow + j)*64 + och);
    Yp[0] = make_float4(acc[j][0], acc[j][1], acc[j][2], acc[j][3]);
    Yp[1] = make_float4(acc[j][4], acc[j][5], acc[j][6], acc[j][7]);
  }
  if (tid < 128) atomicAdd(&stats[128+tid], sStat[tid]);
}

// ---------------- layer 2: fin1 + BN+relu + conv(64->128) + pool ------------
__global__ __launch_bounds__(256) void k_layer2(
    const float* __restrict__ y, const float* __restrict__ W,
    const float* __restrict__ bias, float* stats,
    float* __restrict__ pmax, float* __restrict__ pmin,
    const float* __restrict__ g1, const float* __restrict__ bb1) {
  __shared__ float4 sW4[64*32];
  __shared__ float sB[128], sSc[64], sSh[64];
  __shared__ float sStat[256];
  float* sW = (float*)sW4;
  int tid = threadIdx.x;
  for (int i = tid; i < 64*128; i += 256) {
    int c = i >> 7, o = i & 127;
    sW[i] = W[o*64 + c];
  }
  if (tid < 128) sB[tid] = bias[tid];
  if (tid < 64) {            // fused k_fin for layer-1 stats
    float s = stats[128 + tid], s2 = stats[192 + tid];
    float mean = s * (1.0f/262144.0f);
    float var = fmaxf(s2 * (1.0f/262144.0f) - mean*mean, 0.f);
    float sc = g1[tid] / sqrtf(var + 1e-5f);
    sSc[tid] = sc; sSh[tid] = bb1[tid] - mean * sc;
  }
  sStat[tid] = 0.f;
  __syncthreads();
  int t = blockIdx.x*256 + tid;
  int g = t >> 4;
  int o0 = (t & 15) * 8;
  int w0i = o0 >> 2;
  float mx[8], mn[8], sm[8], sq[8];
#pragma unroll
  for (int i=0;i<8;++i){ mx[i]=-3.4e38f; mn[i]=3.4e38f; sm[i]=0.f; sq[i]=0.f; }
  const float4* Y4 = (const float4*)(y) + (size_t)g*32*16;
#pragma unroll 1
  for (int half = 0; half < 2; ++half) {   // 16-row tile per pass
    float a[16][8];
#pragma unroll
    for (int j=0;j<16;++j)
#pragma unroll
      for (int i=0;i<8;++i) a[j][i] = sB[o0+i];
#pragma unroll 2
    for (int c4 = 0; c4 < 16; ++c4) {      // weights hoisted over 16 rows
      float4 w[8];
#pragma unroll
      for (int ch = 0; ch < 4; ++ch) {
        w[ch*2]   = sW4[(c4*4+ch)*32 + w0i];
        w[ch*2+1] = sW4[(c4*4+ch)*32 + w0i + 1];
      }
      float sc0=sSc[c4*4], sc1=sSc[c4*4+1], sc2=sSc[c4*4+2], sc3=sSc[c4*4+3];
      float sh0=sSh[c4*4], sh1=sSh[c4*4+1], sh2=sSh[c4*4+2], sh3=sSh[c4*4+3];
#pragma unroll
      for (int j = 0; j < 16; ++j) {
        float4 v = Y4[(half*16+j)*16 + c4];
        float r0 = fmaxf(fmaf(v.x, sc0, sh0), 0.f);
        float r1 = fmaxf(fmaf(v.y, sc1, sh1), 0.f);
        float r2 = fmaxf(fmaf(v.z, sc2, sh2), 0.f);
        float r3 = fmaxf(fmaf(v.w, sc3, sh3), 0.f);
        a[j][0]=fmaf(r0,w[0].x,a[j][0]); a[j][1]=fmaf(r0,w[0].y,a[j][1]);
        a[j][2]=fmaf(r0,w[0].z,a[j][2]); a[j][3]=fmaf(r0,w[0].w,a[j][3]);
        a[j][4]=fmaf(r0,w[1].x,a[j][4]); a[j][5]=fmaf(r0,w[1].y,a[j][5]);
        a[j][6]=fmaf(r0,w[1].z,a[j][6]); a[j][7]=fmaf(r0,w[1].w,a[j][7]);
        a[j][0]=fmaf(r1,w[2].x,a[j][0]); a[j][1]=fmaf(r1,w[2].y,a[j][1]);
        a[j][2]=fmaf(r1,w[2].z,a[j][2]); a[j][3]=fmaf(r1,w[2].w,a[j][3]);
        a[j][4]=fmaf(r1,w[3].x,a[j][4]); a[j][5]=fmaf(r1,w[3].y,a[j][5]);
        a[j][6]=fmaf(r1,w[3].z,a[j][6]); a[j][7]=fmaf(r1,w[3].w,a[j][7]);
        a[j][0]=fmaf(r2,w[4].x,a[j][0]); a[j][1]=fmaf(r2,w[4].y,a[j][1]);
        a[j][2]=fmaf(r2,w[4].z,a[j][2]); a[j][3]=fmaf(r2,w[4].w,a[j][3]);
        a[j][4]=fmaf(r2,w[5].x,a[j][4]); a[j][5]=fmaf(r2,w[5].y,a[j][5]);
        a[j][6]=fmaf(r2,w[5].z,a[j][6]); a[j][7]=fmaf(r2,w[5].w,a[j][7]);
        a[j][0]=fmaf(r3,w[6].x,a[j][0]); a[j][1]=fmaf(r3,w[6].y,a[j][1]);
        a[j][2]=fmaf(r3,w[6].z,a[j][2]); a[j][3]=fmaf(r3,w[6].w,a[j][3]);
        a[j][4]=fmaf(r3,w[7].x,a[j][4]); a[j][5]=fmaf(r3,w[7].y,a[j][5]);
        a[j][6]=fmaf(r3,w[7].z,a[j][6]); a[j][7]=fmaf(r3,w[7].w,a[j][7]);
      }
    }
#pragma unroll
    for (int j = 0; j < 16; ++j)
#pragma unroll
      for (int i = 0; i < 8; ++i) {
        float av = a[j][i];
        mx[i]=fmaxf(mx[i],av); mn[i]=fminf(mn[i],av);
        sm[i]=fadd_(sm[i],av); sq[i]=fmaf(av,av,sq[i]);
      }
  }
  size_t ob = (size_t)g*128 + o0;
#pragma unroll
  for (int i=0;i<8;++i) { pmax[ob+i]=mx[i]; pmin[ob+i]=mn[i]; }
#pragma unroll
  for (int i=0;i<8;++i) {
    atomicAdd(&sStat[o0+i], sm[i]);
    atomicAdd(&sStat[128+o0+i], sq[i]);
  }
  __syncthreads();
  atomicAdd(&stats[256+tid], sStat[tid]);
}

// ---------------- output: fin2 + BN+relu on pooled ----------------
__global__ __launch_bounds__(256) void k_out(const float* __restrict__ pmax,
    const float* __restrict__ pmin, const float* __restrict__ stats,
    const float* __restrict__ g2, const float* __restrict__ bb2,
    float* __restrict__ outp) {
  int t = blockIdx.x*256 + threadIdx.x;
  int o = t & 127;
  float s = stats[256 + o], s2 = stats[384 + o];
  float mean = s * (1.0f/262144.0f);
  float var = fmaxf(s2 * (1.0f/262144.0f) - mean*mean, 0.f);
  float sc = g2[o] / sqrtf(var + 1e-5f);
  float sh = bb2[o] - mean * sc;
  float sel = (sc >= 0.f) ? pmax[t] : pmin[t];
  outp[t] = fmaxf(fmaf(sel, sc, sh), 0.f);
}

extern "C" void kernel_launch(void* const* d_in, const int* in_sizes, int n_in,
                              void* d_out, int out_size, void* d_ws, size_t ws_size,
                              hipStream_t stream) {
  const float* xyz = (const float*)d_in[0];
  const float* pts = (const float*)d_in[1];
  const float* W0  = (const float*)d_in[2];
  const float* b0  = (const float*)d_in[3];
  const float* g0  = (const float*)d_in[4];
  const float* bb0 = (const float*)d_in[5];
  const float* W1  = (const float*)d_in[6];
  const float* b1  = (const float*)d_in[7];
  const float* g1  = (const float*)d_in[8];
  const float* bb1 = (const float*)d_in[9];
  const float* W2  = (const float*)d_in[10];
  const float* b2  = (const float*)d_in[11];
  const float* g2  = (const float*)d_in[12];
  const float* bb2 = (const float*)d_in[13];
  float* out_nx = (float*)d_out;
  float* out_np = out_nx + (size_t)NB*NS*3;
  float* ws = (float*)d_ws;
  float* stats = ws;                               // 1024 floats
  int* gidx = (int*)(ws + 1024);                   // NROWS ints
  float* ybuf = ws + 1024 + NROWS;                 // NROWS*64 floats
  float* pmax = ybuf + (size_t)NROWS*64;           // NB*NS*128
  float* pmin = pmax + (size_t)NB*NS*128;          // NB*NS*128

  k_fps<<<NB, 512, 0, stream>>>(xyz, out_nx);
  k_query<<<2048, 256, 0, stream>>>(xyz, out_nx, gidx, stats);
  k_layer0<<<1024, 256, 0, stream>>>(xyz, pts, out_nx, gidx, W0, b0, ybuf, stats);
  k_layer1<<<1024, 256, 0, stream>>>(ybuf, W1, b1, stats, g0, bb0);
  k_layer2<<<512, 256, 0, stream>>>(ybuf, W2, b2, stats, pmax, pmin, g1, bb1);
  k_out<<<4096, 256, 0, stream>>>(pmax, pmin, stats, g2, bb2, out_np);
}